// Round 7
// baseline (627.575 us; speedup 1.0000x reference)
//
#include <hip/hip_runtime.h>
#include <hip/hip_bf16.h>
#include <math.h>

#define B_ 4
#define S_ 2048
#define D_ 1024
#define M_ (B_*S_)   // 8192 rows total across batch
#define MBYTE (1024ull*1024ull)

typedef __attribute__((ext_vector_type(8))) _Float16 f16x8;  // 8 f16 = 4 VGPRs (MFMA A/B frag)
typedef __attribute__((ext_vector_type(4))) float f32x4;     // MFMA C/D frag
typedef __attribute__((ext_vector_type(8))) unsigned short us8;
typedef unsigned short us;

__device__ inline us f2h(float f) {
    union { _Float16 h; us u; } x;
    x.h = (_Float16)f;   // RTE
    return x.u;
}
__device__ inline float h2f(us u) {
    union { us u; _Float16 h; } x; x.u = u;
    return (float)x.h;
}

__device__ inline void gload16(const us* g, us* l) {
    __builtin_amdgcn_global_load_lds(
        (const __attribute__((address_space(1))) unsigned int*)g,
        (__attribute__((address_space(3))) unsigned int*)l, 16, 0, 0);
}

// ---------------------------------------------------------------------------
// Split cast: f32 -> hi fp16 (+ lo fp16 residual if DO_LO). 4 elems/thread.
// ---------------------------------------------------------------------------
template<int DO_LO>
__global__ __launch_bounds__(256)
void cast2_k(const float* __restrict__ in, us* __restrict__ hi, us* __restrict__ lo) {
    const size_t i = ((size_t)blockIdx.x * 256 + threadIdx.x) * 4;
    const float4 v = *(const float4*)&in[i];
    ushort4 h;
    h.x = f2h(v.x); h.y = f2h(v.y); h.z = f2h(v.z); h.w = f2h(v.w);
    *(ushort4*)&hi[i] = h;
    if (DO_LO) {
        ushort4 l;
        l.x = f2h(v.x - h2f(h.x)); l.y = f2h(v.y - h2f(h.y));
        l.z = f2h(v.z - h2f(h.z)); l.w = f2h(v.w - h2f(h.w));
        *(ushort4*)&lo[i] = l;
    }
}

// ---------------------------------------------------------------------------
// Weight transpose + split cast: W fp32 [K][N] -> Wt1(,Wt2) fp16 [N][K].
// ---------------------------------------------------------------------------
template<int DO_LO>
__global__ __launch_bounds__(256)
void wsplit_k(const float* __restrict__ W, us* __restrict__ Wt1, us* __restrict__ Wt2) {
    __shared__ float t[64][65];
    const int tid = threadIdx.x;
    const int k0 = blockIdx.x*64, n0 = blockIdx.y*64;
    #pragma unroll
    for (int i = 0; i < 4; ++i) {
        const int c = i*256 + tid;
        const int row = c >> 4, col = (c & 15) * 4;
        const float4 v = *(const float4*)&W[(size_t)(k0+row)*D_ + n0+col];
        t[row][col]=v.x; t[row][col+1]=v.y; t[row][col+2]=v.z; t[row][col+3]=v.w;
    }
    __syncthreads();
    #pragma unroll
    for (int i = 0; i < 4; ++i) {
        const int c = i*256 + tid;
        const int n = c >> 4, k = (c & 15) * 4;
        float f[4] = { t[k][n], t[k+1][n], t[k+2][n], t[k+3][n] };
        ushort4 h;
        h.x=f2h(f[0]); h.y=f2h(f[1]); h.z=f2h(f[2]); h.w=f2h(f[3]);
        *(ushort4*)&Wt1[(size_t)(n0+n)*D_ + k0+k] = h;
        if (DO_LO) {
            ushort4 l;
            l.x=f2h(f[0]-h2f(h.x)); l.y=f2h(f[1]-h2f(h.y));
            l.z=f2h(f[2]-h2f(h.z)); l.w=f2h(f[3]-h2f(h.w));
            *(ushort4*)&Wt2[(size_t)(n0+n)*D_ + k0+k] = l;
        }
    }
}

// ---------------------------------------------------------------------------
// bkr[j] = sum_k bk[k]*Wr[k][j] + br[j]  (tiny fused-bias precompute)
// ---------------------------------------------------------------------------
__global__ __launch_bounds__(256)
void bkr_k(const float* __restrict__ bk, const float* __restrict__ Wr,
           const float* __restrict__ br, float* __restrict__ bkr) {
    const int j = blockIdx.x*256 + threadIdx.x;
    float acc = 0.f;
    for (int k = 0; k < D_; ++k) acc += bk[k] * Wr[(size_t)k*D_ + j];
    bkr[j] = acc + br[j];
}

// ---------------------------------------------------------------------------
// V transpose: fp16 [b][s][d] -> fp16 [b][d][s]
// ---------------------------------------------------------------------------
__global__ __launch_bounds__(256)
void vtrans_k(const us* __restrict__ V, us* __restrict__ Vt) {
    __shared__ us t[64][68];
    const int tid = threadIdx.x;
    const int s0 = blockIdx.x*64, d0 = blockIdx.y*64, b = blockIdx.z;
    const us* Vb  = V  + (size_t)b*S_*D_;
    us*       Vtb = Vt + (size_t)b*D_*S_;
    #pragma unroll
    for (int i = 0; i < 4; ++i) {
        const int c = i*256 + tid;
        const int row = c >> 4, col = (c & 15) * 4;
        *(ushort4*)&t[row][col] = *(const ushort4*)&Vb[(size_t)(s0+row)*D_ + d0+col];
    }
    __syncthreads();
    #pragma unroll
    for (int i = 0; i < 4; ++i) {
        const int c = i*256 + tid;
        const int d = c >> 4, s = (c & 15) * 4;
        ushort4 o;
        o.x = t[s][d]; o.y = t[s+1][d]; o.z = t[s+2][d]; o.w = t[s+3][d];
        *(ushort4*)&Vtb[(size_t)(d0+d)*S_ + s0+s] = o;
    }
}

// ---------------------------------------------------------------------------
// fp16 MFMA GEMM: C[M][N] = A[M][K] @ Bt[N][K]^T, fp32 accumulate.
// 128x128 tile, 4 waves 2x2, global_load_lds width-16 staging.
// blockIdx.x = M-tile (XCD = blk%8 -> A-panel L2 sharing per XCD).
// LDS content swizzle: slot s of row r holds global chunk s^f(r) so the
// fragment ds_read_b128 spreads banks (2-way aliasing = free, m136).
// f(r) = (r>>1)&3 for BK=32, r&7 for BK=64.
// SPLIT=1: A=A1+A2, B=B1+B2 (fp16 hi/lo); A1B1+A1B2+A2B1 = fp32-grade.
// EPI: 0 = fp32 store; 1 = f16(acc+bias); 2 = f16(cos(acc+bias));
//      3 = split f16 store (+bias); 4 = split f16 store (no bias).
// ---------------------------------------------------------------------------
template<int Nv, int Kv, int BK, int SPLIT, int EPI>
__global__ __launch_bounds__(256)
void gemm_bt_k(const us* __restrict__ A1, const us* __restrict__ A2,
               const us* __restrict__ B1, const us* __restrict__ B2,
               const float* __restrict__ bias, void* __restrict__ Cv,
               us* __restrict__ C2, long sA, long sB, long sC) {
    constexpr int TPR = BK/8;            // 16B chunks per row
    constexpr int NP  = BK/16;           // staging passes of 256 threads
    constexpr int NARR = (SPLIT?4:2);
    constexpr int SM = (NARR*128*BK > 16384) ? NARR*128*BK : 16384;
    __shared__ us smem[SM];
    us* As  = smem;
    us* As2 = smem + 128*BK;
    us* Bs  = smem + (SPLIT?2:1)*128*BK;
    us* Bs2 = Bs + 128*BK;
    const int tid = threadIdx.x;
    const us* A1b = A1 + (size_t)blockIdx.z * sA;
    const us* A2b = SPLIT ? A2 + (size_t)blockIdx.z * sA : nullptr;
    const us* B1b = B1 + (size_t)blockIdx.z * sB;
    const us* B2b = SPLIT ? B2 + (size_t)blockIdx.z * sB : nullptr;
    const int m0 = blockIdx.x * 128, n0 = blockIdx.y * 128;
    const int lane = tid & 63, w = tid >> 6;
    const int mw = (w >> 1) * 64, nw = (w & 1) * 64;
    const int lr = lane & 15, lq = lane >> 4;

    f32x4 acc[4][4];
    #pragma unroll
    for (int i = 0; i < 4; ++i)
        #pragma unroll
        for (int j = 0; j < 4; ++j)
            acc[i][j] = (f32x4){0.f, 0.f, 0.f, 0.f};

    for (int kc = 0; kc < Kv; kc += BK) {
        #pragma unroll
        for (int p = 0; p < NP; ++p) {
            const int idx = p*256 + tid;
            const int r = idx / TPR, s = idx % TPR;
            const int gc = (BK==32) ? (s ^ ((r>>1)&3)) : (s ^ (r&7));
            const size_t ga = (size_t)(m0 + r) * Kv + kc + gc*8;
            const size_t gb = (size_t)(n0 + r) * Kv + kc + gc*8;
            gload16(&A1b[ga], &As[(size_t)idx*8]);
            gload16(&B1b[gb], &Bs[(size_t)idx*8]);
            if (SPLIT) {
                gload16(&A2b[ga], &As2[(size_t)idx*8]);
                gload16(&B2b[gb], &Bs2[(size_t)idx*8]);
            }
        }
        __syncthreads();
        #pragma unroll
        for (int kk = 0; kk < BK; kk += 32) {
            int sa[4], sb[4];
            #pragma unroll
            for (int i = 0; i < 4; ++i) {
                const int ra = mw + i*16 + lr;
                const int c  = lq + (kk>>5)*4;
                const int sl = (BK==32) ? (lq ^ ((ra>>1)&3)) : (c ^ (ra&7));
                sa[i] = ra*BK + sl*8;
                const int rb = nw + i*16 + lr;
                const int slb = (BK==32) ? (lq ^ ((rb>>1)&3)) : (c ^ (rb&7));
                sb[i] = rb*BK + slb*8;
            }
            f16x8 a1[4], b1[4];
            #pragma unroll
            for (int i = 0; i < 4; ++i) a1[i] = *(const f16x8*)&As[sa[i]];
            #pragma unroll
            for (int j = 0; j < 4; ++j) b1[j] = *(const f16x8*)&Bs[sb[j]];
            if (SPLIT) {
                f16x8 a2[4], b2[4];
                #pragma unroll
                for (int i = 0; i < 4; ++i) a2[i] = *(const f16x8*)&As2[sa[i]];
                #pragma unroll
                for (int j = 0; j < 4; ++j) b2[j] = *(const f16x8*)&Bs2[sb[j]];
                #pragma unroll
                for (int i = 0; i < 4; ++i)
                    #pragma unroll
                    for (int j = 0; j < 4; ++j) {
                        acc[i][j] = __builtin_amdgcn_mfma_f32_16x16x32_f16(a2[i], b1[j], acc[i][j], 0, 0, 0);
                        acc[i][j] = __builtin_amdgcn_mfma_f32_16x16x32_f16(a1[i], b2[j], acc[i][j], 0, 0, 0);
                        acc[i][j] = __builtin_amdgcn_mfma_f32_16x16x32_f16(a1[i], b1[j], acc[i][j], 0, 0, 0);
                    }
            } else {
                #pragma unroll
                for (int i = 0; i < 4; ++i)
                    #pragma unroll
                    for (int j = 0; j < 4; ++j)
                        acc[i][j] = __builtin_amdgcn_mfma_f32_16x16x32_f16(a1[i], b1[j], acc[i][j], 0, 0, 0);
            }
        }
        __syncthreads();
    }

    // ---------------- coalesced epilogue (per-wave 8KB LDS slab) ----------
    float* slab = (float*)smem + (size_t)w * 2048;   // 32x64 fp32
    const int lrow0 = lane >> 3, cb = (lane & 7) * 8;
    #pragma unroll
    for (int p = 0; p < 2; ++p) {
        #pragma unroll
        for (int ii = 0; ii < 2; ++ii) {
            const int i = p*2 + ii;
            #pragma unroll
            for (int j = 0; j < 4; ++j)
                #pragma unroll
                for (int r = 0; r < 4; ++r)
                    slab[(ii*16 + lq*4 + r)*64 + j*16 + lr] = acc[i][j][r];
        }
        __syncthreads();
        #pragma unroll
        for (int t = 0; t < 4; ++t) {
            const int lrow = t*8 + lrow0;
            const int grow = m0 + mw + p*32 + lrow;
            const int gcol = n0 + nw + cb;
            const size_t idx = (size_t)grow * Nv + gcol;
            float v[8];
            #pragma unroll
            for (int u = 0; u < 8; ++u) v[u] = slab[lrow*64 + cb + u];
            if (EPI == 0) {
                float* Cf = (float*)Cv + (size_t)blockIdx.z * sC;
                float4 o0 = {v[0],v[1],v[2],v[3]}, o1 = {v[4],v[5],v[6],v[7]};
                *(float4*)&Cf[idx] = o0;
                *(float4*)&Cf[idx+4] = o1;
            } else if (EPI == 1 || EPI == 2) {
                us8 o;
                #pragma unroll
                for (int u = 0; u < 8; ++u) {
                    const float tv = v[u] + bias[gcol + u];
                    o[u] = f2h(EPI == 2 ? cosf(tv) : tv);
                }
                *(us8*)&((us*)Cv)[idx] = o;
            } else {
                us8 oh, ol;
                #pragma unroll
                for (int u = 0; u < 8; ++u) {
                    const float tv = v[u] + ((EPI == 3) ? bias[gcol + u] : 0.f);
                    const us hh = f2h(tv);
                    oh[u] = hh;
                    ol[u] = f2h(tv - h2f(hh));
                }
                *(us8*)&((us*)Cv)[idx] = oh;
                *(us8*)&C2[idx] = ol;
            }
        }
        __syncthreads();
    }
}

// ---------------------------------------------------------------------------
// Row softmax: S fp32 [S_] per row -> normalized P fp16. One block per row.
// ---------------------------------------------------------------------------
__global__ __launch_bounds__(256)
void softmax_k(const float* __restrict__ S, us* __restrict__ P) {
    __shared__ float red[8];
    const int tid = threadIdx.x;
    const int lane = tid & 63, w = tid >> 6;
    const float* row = S + (size_t)blockIdx.x * S_;

    const float4 v0 = *(const float4*)&row[tid*8];
    const float4 v1 = *(const float4*)&row[tid*8 + 4];
    float e[8] = {v0.x, v0.y, v0.z, v0.w, v1.x, v1.y, v1.z, v1.w};

    float mx = e[0];
    #pragma unroll
    for (int j = 1; j < 8; ++j) mx = fmaxf(mx, e[j]);
    #pragma unroll
    for (int off = 1; off < 64; off <<= 1) mx = fmaxf(mx, __shfl_xor(mx, off));
    if (lane == 0) red[w] = mx;
    __syncthreads();
    mx = fmaxf(fmaxf(red[0], red[1]), fmaxf(red[2], red[3]));

    float sum = 0.f;
    #pragma unroll
    for (int j = 0; j < 8; ++j) { e[j] = __expf(e[j] - mx); sum += e[j]; }
    #pragma unroll
    for (int off = 1; off < 64; off <<= 1) sum += __shfl_xor(sum, off);
    if (lane == 0) red[4 + w] = sum;
    __syncthreads();
    const float inv = 1.0f / (red[4] + red[5] + red[6] + red[7]);

    us8 o;
    #pragma unroll
    for (int j = 0; j < 8; ++j) o[j] = f2h(e[j] * inv);
    *(us8*)&P[(size_t)blockIdx.x * S_ + tid*8] = o;
}

// ---------------------------------------------------------------------------
extern "C" void kernel_launch(void* const* d_in, const int* in_sizes, int n_in,
                              void* d_out, int out_size, void* d_ws, size_t ws_size,
                              hipStream_t stream) {
    const float* x  = (const float*)d_in[0];
    const float* y  = (const float*)d_in[1];
    const float* Wq = (const float*)d_in[2];
    const float* bq = (const float*)d_in[3];
    const float* Wk = (const float*)d_in[4];
    const float* bk = (const float*)d_in[5];
    const float* Wv = (const float*)d_in[6];
    const float* bv = (const float*)d_in[7];
    const float* Wr = (const float*)d_in[8];
    const float* br = (const float*)d_in[9];
    float* out = (float*)d_out;

    // Workspace (96 MB) choreography:
    //  [ 0,16) Vt
    //  [16,32) Wk1,Wk2,Wr1,Wr2,WkrT1,WkrT2,Wq1,Wv1 (2 MB each) -> P(b0,b1)
    //  [32,48) y1 (dead after V GEMM)                          -> P(b2,b3)
    //  [48,64) Qb
    //  [64,80) Kh
    //  [80,96) y2 -> xh -> Sb (fp32, per batch)
    // d_out doubles as scratch: [0,16) Vh fp16, 16 MB offset: bkr (4 KB);
    // both dead before the final PV GEMM overwrites d_out.
    char* wsb = (char*)d_ws;
    us*    Vt    = (us*)(wsb +  0*MBYTE);
    us*    Wk1   = (us*)(wsb + 16*MBYTE);
    us*    Wk2   = (us*)(wsb + 18*MBYTE);
    us*    Wr1   = (us*)(wsb + 20*MBYTE);
    us*    Wr2   = (us*)(wsb + 22*MBYTE);
    us*    WkrT1 = (us*)(wsb + 24*MBYTE);
    us*    WkrT2 = (us*)(wsb + 26*MBYTE);
    us*    Wq1   = (us*)(wsb + 28*MBYTE);
    us*    Wv1   = (us*)(wsb + 30*MBYTE);
    us*    Pb    = (us*)(wsb + 16*MBYTE);
    us*    y1    = (us*)(wsb + 32*MBYTE);
    us*    Qb    = (us*)(wsb + 48*MBYTE);
    us*    Kh    = (us*)(wsb + 64*MBYTE);
    us*    y2    = (us*)(wsb + 80*MBYTE);
    us*    xh    = (us*)(wsb + 80*MBYTE);
    float* Sb    = (float*)(wsb + 80*MBYTE);
    us*    Vh    = (us*)d_out;                          // scratch in out buf
    float* bkrP  = (float*)d_out + 4*1024*1024;         // 16 MB offset

    const dim3 bb(256);

    // --- fused K chain: Khat = cos(y@(Wk@Wr) + bk@Wr + br) ---
    cast2_k<1><<<dim3(M_*D_/1024), bb, 0, stream>>>(y, y1, y2);
    cast2_k<1><<<dim3(D_*D_/1024), bb, 0, stream>>>(Wk, Wk1, Wk2);
    wsplit_k<1><<<dim3(16,16), bb, 0, stream>>>(Wr, Wr1, Wr2);
    bkr_k<<<dim3(D_/256), bb, 0, stream>>>(bk, Wr, br, bkrP);
    // WkrT[j][k] = sum_m Wr[m][j]*Wk[k][m]: A = Wr^T (wsplit), Bt = Wk (cast2).
    // (Round 6 bug: computed Wkr row-major and fed it as Bt, i.e. transposed.)
    gemm_bt_k<D_, D_, 32, 1, 4><<<dim3(D_/128, D_/128), bb, 0, stream>>>(
        Wr1, Wr2, Wk1, Wk2, nullptr, (void*)WkrT1, WkrT2, 0, 0, 0);
    gemm_bt_k<D_, D_, 32, 1, 2><<<dim3(M_/128, D_/128), bb, 0, stream>>>(
        y1, y2, WkrT1, WkrT2, bkrP, (void*)Kh, nullptr, 0, 0, 0);

    // --- Q, V (plain fp16 MFMA) ---
    cast2_k<0><<<dim3(M_*D_/1024), bb, 0, stream>>>(x, xh, nullptr);
    wsplit_k<0><<<dim3(16,16), bb, 0, stream>>>(Wq, Wq1, nullptr);
    gemm_bt_k<D_, D_, 64, 0, 1><<<dim3(M_/128, D_/128), bb, 0, stream>>>(
        xh, nullptr, Wq1, nullptr, bq, (void*)Qb, nullptr, 0, 0, 0);
    wsplit_k<0><<<dim3(16,16), bb, 0, stream>>>(Wv, Wv1, nullptr);
    gemm_bt_k<D_, D_, 64, 0, 1><<<dim3(M_/128, D_/128), bb, 0, stream>>>(
        y1, nullptr, Wv1, nullptr, bv, (void*)Vh, nullptr, 0, 0, 0);
    vtrans_k<<<dim3(S_/64, D_/64, B_), bb, 0, stream>>>(Vh, Vt);

    // --- attention core ---
    for (int b = 0; b < B_; ++b) {
        gemm_bt_k<S_, D_, 64, 0, 0><<<dim3(S_/128, S_/128, 1), bb, 0, stream>>>(
            Qb + (size_t)b*S_*D_, nullptr, Kh + (size_t)b*S_*D_, nullptr,
            nullptr, (void*)Sb, nullptr, 0, 0, 0);
        softmax_k<<<dim3(S_), bb, 0, stream>>>(Sb, Pb + (size_t)b*S_*S_);
    }
    gemm_bt_k<D_, S_, 64, 0, 0><<<dim3(S_/128, D_/128, B_), bb, 0, stream>>>(
        Pb, nullptr, Vt, nullptr, nullptr, (void*)out, nullptr,
        (long)S_*S_, (long)D_*S_, (long)S_*D_);
}